// Round 9
// baseline (271.333 us; speedup 1.0000x reference)
//
#include <hip/hip_runtime.h>
#include <math.h>

#define NENTITY   100000
#define NRELATION 500
#define HID       100
#define HOUSE_DIM 4
#define HOUSE_NUM 10
#define B_SZ      512
#define NEG       256
#define THRED     0.5f
#define GAMMA     12.0f

#define SEGS           4                    // main blocks per batch row
#define NEG_PER_BLOCK  (NEG / SEGS)         // 64
#define BLOCK          256                  // 4 waves
#define NEG_PER_WAVE   (NEG_PER_BLOCK / 4)  // 16

// d_ws layout (float4/float2 arrays):
#define WS_F4_STRIDE (B_SZ * HID)

// entity table: NENTITY*HID float4s = 10,000,000 float4
#define ENT_F4_TOTAL (NENTITY * HID)

__device__ __forceinline__ float dot4(const float4 a, const float4 b) {
    return a.x * b.x + a.y * b.y + a.z * b.z + a.w * b.w;
}

__device__ __forceinline__ float4 norm4(float4 v) {
    const float n = fmaxf(sqrtf(dot4(v, v)), 1e-12f);
    const float inv = 1.0f / n;
    v.x *= inv; v.y *= inv; v.z *= inv; v.w *= inv;
    return v;
}

__device__ __forceinline__ float4 reflect4(float4 x, const float4 v, const float coef) {
    const float s = coef * dot4(v, x);
    x.x -= s * v.x; x.y -= s * v.y; x.z -= s * v.z; x.w -= s * v.w;
    return x;
}

// two tail reflections then ||hd - tv||
__device__ __forceinline__ float hdist(float4 tv, const float4 v0, const float4 v1,
                                       const float2 kt, const float4 hd) {
    const float s0 = kt.x * dot4(v0, tv);
    tv.x -= s0 * v0.x; tv.y -= s0 * v0.y; tv.z -= s0 * v0.z; tv.w -= s0 * v0.w;
    const float s1 = kt.y * dot4(v1, tv);
    tv.x -= s1 * v1.x; tv.y -= s1 * v1.y; tv.z -= s1 * v1.z; tv.w -= s1 * v1.w;
    const float dx = hd.x - tv.x;
    const float dy = hd.y - tv.y;
    const float dz = hd.z - tv.z;
    const float dw = hd.w - tv.w;
    return sqrtf(dx * dx + dy * dy + dz * dz + dw * dw);
}

// ---- Kernel P: sequential stream of the entity table to warm the L3.
//      Stream-ordered before the score kernel; converts random DRAM gathers
//      into (sequential DRAM fill) + (random L3 hits). ----
__global__ __launch_bounds__(256) void ent_prefetch_kernel(
    const float4* __restrict__ ent4)
{
    const int nthreads = gridDim.x * 256;
    float sx = 0.0f, sy = 0.0f;
    for (size_t i = blockIdx.x * 256 + threadIdx.x; i < ENT_F4_TOTAL; i += nthreads) {
        const float4 v = ent4[i];
        sx += v.x + v.z;
        sy += v.y + v.w;
    }
    // keep loads live without any observable side effect (rule #17)
    asm volatile("" :: "v"(sx), "v"(sy));
}

// ---- Kernel A: per-(b,hid) prep, once per batch row ----
__global__ __launch_bounds__(128) void house_prep_kernel(
    const float* __restrict__ ent,
    const float* __restrict__ rel,
    const float* __restrict__ kdh,
    const float* __restrict__ kdt,
    const float* __restrict__ ksh,
    const float* __restrict__ kst,
    const int* __restrict__ head_idx,
    const int* __restrict__ rel_idx,
    float* __restrict__ ws)
{
    const int b = blockIdx.x;
    const int h = threadIdx.x;
    if (h >= HID) return;
    const int r = rel_idx[b];

    const float4* rr = (const float4*)(rel + ((size_t)r * HID + h) * (HOUSE_NUM * HOUSE_DIM));

    const int he = head_idx[b];
    float4 hd = ((const float4*)ent)[(size_t)he * HID + h];

    const float kh0 = fminf(kdh[r * 2 + 0] * fabsf(ksh[((size_t)r * HID + h) * 2 + 0]), THRED);
    const float kh1 = fminf(kdh[r * 2 + 1] * fabsf(ksh[((size_t)r * HID + h) * 2 + 1]), THRED);

    hd = reflect4(hd, norm4(rr[9]), kh0);
    hd = reflect4(hd, norm4(rr[8]), kh1);
    #pragma unroll
    for (int j = 7; j >= 2; --j) hd = reflect4(hd, norm4(rr[j]), 2.0f);

    const float kt0 = fminf(kdt[r * 2 + 0] * fabsf(kst[((size_t)r * HID + h) * 2 + 0]), THRED);
    const float kt1 = fminf(kdt[r * 2 + 1] * fabsf(kst[((size_t)r * HID + h) * 2 + 1]), THRED);

    float4* wsHead = (float4*)ws;
    float4* wsV0   = wsHead + WS_F4_STRIDE;
    float4* wsV1   = wsV0 + WS_F4_STRIDE;
    float2* wsKt   = (float2*)(wsV1 + WS_F4_STRIDE);

    const int idx = b * HID + h;
    wsHead[idx] = hd;
    wsV0[idx]   = norm4(rr[0]);
    wsV1[idx]   = norm4(rr[1]);
    wsKt[idx]   = make_float2(kt0, kt1);
}

// ---- Kernel B: cooperative gather + score, 4 negs batched per iteration ----
__global__ __launch_bounds__(BLOCK, 5) void house_score_kernel(
    const float* __restrict__ ent,
    const int* __restrict__ tail_idx,
    const float* __restrict__ ws,
    float* __restrict__ out)
{
    const int blk = blockIdx.x;
    const int b   = blk >> 2;          // SEGS = 4
    const int seg = blk & (SEGS - 1);
    const int tid = threadIdx.x;
    const int w = tid >> 6;   // wave in block
    const int l = tid & 63;   // lane

    const float4* wsHead = (const float4*)ws;
    const float4* wsV0   = wsHead + WS_F4_STRIDE;
    const float4* wsV1   = wsV0 + WS_F4_STRIDE;
    const float2* wsKt   = (const float2*)(wsV1 + WS_F4_STRIDE);

    // lane l owns hids {l, 64+l (l<36)}
    const int i1 = b * HID + l;
    const float4 hd1 = wsHead[i1];
    const float4 v01 = wsV0[i1];
    const float4 v11 = wsV1[i1];
    const float2 k1  = wsKt[i1];
    const int   l2   = (l < 36) ? (64 + l) : 99;
    const int   i2   = b * HID + l2;
    const float4 hd2 = wsHead[i2];
    const float4 v02 = wsV0[i2];
    const float4 v12 = wsV1[i2];
    const float2 k2  = wsKt[i2];
    const bool has2  = (l < 36);

    const int negbase = seg * NEG_PER_BLOCK + w * NEG_PER_WAVE;

    // this wave's 16 tail indices live in lanes 0..15
    int my_e = 0;
    if (l < NEG_PER_WAVE) my_e = tail_idx[(size_t)b * NEG + negbase + l];

    const float4* entf4 = (const float4*)ent;

    for (int ii = 0; ii < NEG_PER_WAVE; ii += 4) {
        const int e0 = __shfl(my_e, ii + 0);
        const int e1 = __shfl(my_e, ii + 1);
        const int e2 = __shfl(my_e, ii + 2);
        const int e3 = __shfl(my_e, ii + 3);
        const float4* r0 = entf4 + (size_t)e0 * HID;
        const float4* r1 = entf4 + (size_t)e1 * HID;
        const float4* r2 = entf4 + (size_t)e2 * HID;
        const float4* r3 = entf4 + (size_t)e3 * HID;

        // issue all 8 row-segment loads before any compute (deep MLP)
        const float4 a0 = r0[l];
        const float4 a1 = r1[l];
        const float4 a2 = r2[l];
        const float4 a3 = r3[l];
        float4 b0, b1, b2, b3;
        if (has2) {
            b0 = r0[64 + l];
            b1 = r1[64 + l];
            b2 = r2[64 + l];
            b3 = r3[64 + l];
        }

        float s0 = hdist(a0, v01, v11, k1, hd1);
        float s1 = hdist(a1, v01, v11, k1, hd1);
        float s2 = hdist(a2, v01, v11, k1, hd1);
        float s3 = hdist(a3, v01, v11, k1, hd1);
        if (has2) {
            s0 += hdist(b0, v02, v12, k2, hd2);
            s1 += hdist(b1, v02, v12, k2, hd2);
            s2 += hdist(b2, v02, v12, k2, hd2);
            s3 += hdist(b3, v02, v12, k2, hd2);
        }

        // 4 interleaved butterfly reductions (independent DS chains)
        #pragma unroll
        for (int m = 1; m < 64; m <<= 1) {
            s0 += __shfl_xor(s0, m);
            s1 += __shfl_xor(s1, m);
            s2 += __shfl_xor(s2, m);
            s3 += __shfl_xor(s3, m);
        }

        if (l == 0) {
            float4 o = make_float4(GAMMA - s0, GAMMA - s1, GAMMA - s2, GAMMA - s3);
            *(float4*)(out + (size_t)b * NEG + negbase + ii) = o;
        }
    }
}

extern "C" void kernel_launch(void* const* d_in, const int* in_sizes, int n_in,
                              void* d_out, int out_size, void* d_ws, size_t ws_size,
                              hipStream_t stream) {
    const float* ent = (const float*)d_in[0];
    const float* rel = (const float*)d_in[1];
    const float* kdh = (const float*)d_in[2];
    const float* kdt = (const float*)d_in[3];
    const float* ksh = (const float*)d_in[4];
    const float* kst = (const float*)d_in[5];
    const int* head_idx = (const int*)d_in[6];
    const int* rel_idx  = (const int*)d_in[7];
    const int* tail_idx = (const int*)d_in[8];
    float* out = (float*)d_out;
    float* ws  = (float*)d_ws;

    // warm L3 with the entity table (serializes before the score kernel)
    ent_prefetch_kernel<<<2048, 256, 0, stream>>>((const float4*)ent);
    house_prep_kernel<<<B_SZ, 128, 0, stream>>>(
        ent, rel, kdh, kdt, ksh, kst, head_idx, rel_idx, ws);
    house_score_kernel<<<B_SZ * SEGS, BLOCK, 0, stream>>>(
        ent, tail_idx, ws, out);
}

// Round 10
// 244.951 us; speedup vs baseline: 1.1077x; 1.1077x over previous
//
#include <hip/hip_runtime.h>
#include <math.h>

#define NENTITY   100000
#define NRELATION 500
#define HID       100
#define HOUSE_DIM 4
#define HOUSE_NUM 10
#define B_SZ      512
#define NEG       256
#define THRED     0.5f
#define GAMMA     12.0f

#define SEGS           4                    // main blocks per batch row
#define NEG_PER_BLOCK  (NEG / SEGS)         // 64
#define BLOCK          256                  // 4 waves
#define NEG_PER_WAVE   (NEG_PER_BLOCK / 4)  // 16

// d_ws layout (float4/float2 arrays):
#define WS_F4_STRIDE (B_SZ * HID)

typedef float vfloat4 __attribute__((ext_vector_type(4)));

__device__ __forceinline__ float4 ntload4(const float4* p) {
    vfloat4 v = __builtin_nontemporal_load((const vfloat4*)p);
    return make_float4(v.x, v.y, v.z, v.w);
}

__device__ __forceinline__ float dot4(const float4 a, const float4 b) {
    return a.x * b.x + a.y * b.y + a.z * b.z + a.w * b.w;
}

__device__ __forceinline__ float4 norm4(float4 v) {
    const float n = fmaxf(sqrtf(dot4(v, v)), 1e-12f);
    const float inv = 1.0f / n;
    v.x *= inv; v.y *= inv; v.z *= inv; v.w *= inv;
    return v;
}

__device__ __forceinline__ float4 reflect4(float4 x, const float4 v, const float coef) {
    const float s = coef * dot4(v, x);
    x.x -= s * v.x; x.y -= s * v.y; x.z -= s * v.z; x.w -= s * v.w;
    return x;
}

// two tail reflections then ||hd - tv||
__device__ __forceinline__ float hdist(float4 tv, const float4 v0, const float4 v1,
                                       const float2 kt, const float4 hd) {
    const float s0 = kt.x * dot4(v0, tv);
    tv.x -= s0 * v0.x; tv.y -= s0 * v0.y; tv.z -= s0 * v0.z; tv.w -= s0 * v0.w;
    const float s1 = kt.y * dot4(v1, tv);
    tv.x -= s1 * v1.x; tv.y -= s1 * v1.y; tv.z -= s1 * v1.z; tv.w -= s1 * v1.w;
    const float dx = hd.x - tv.x;
    const float dy = hd.y - tv.y;
    const float dz = hd.z - tv.z;
    const float dw = hd.w - tv.w;
    return sqrtf(dx * dx + dy * dy + dz * dz + dw * dw);
}

// ---- Kernel A: per-(b,hid) prep, once per batch row ----
__global__ __launch_bounds__(128) void house_prep_kernel(
    const float* __restrict__ ent,
    const float* __restrict__ rel,
    const float* __restrict__ kdh,
    const float* __restrict__ kdt,
    const float* __restrict__ ksh,
    const float* __restrict__ kst,
    const int* __restrict__ head_idx,
    const int* __restrict__ rel_idx,
    float* __restrict__ ws)
{
    const int b = blockIdx.x;
    const int h = threadIdx.x;
    if (h >= HID) return;
    const int r = rel_idx[b];

    const float4* rr = (const float4*)(rel + ((size_t)r * HID + h) * (HOUSE_NUM * HOUSE_DIM));

    const int he = head_idx[b];
    float4 hd = ((const float4*)ent)[(size_t)he * HID + h];

    const float kh0 = fminf(kdh[r * 2 + 0] * fabsf(ksh[((size_t)r * HID + h) * 2 + 0]), THRED);
    const float kh1 = fminf(kdh[r * 2 + 1] * fabsf(ksh[((size_t)r * HID + h) * 2 + 1]), THRED);

    hd = reflect4(hd, norm4(rr[9]), kh0);
    hd = reflect4(hd, norm4(rr[8]), kh1);
    #pragma unroll
    for (int j = 7; j >= 2; --j) hd = reflect4(hd, norm4(rr[j]), 2.0f);

    const float kt0 = fminf(kdt[r * 2 + 0] * fabsf(kst[((size_t)r * HID + h) * 2 + 0]), THRED);
    const float kt1 = fminf(kdt[r * 2 + 1] * fabsf(kst[((size_t)r * HID + h) * 2 + 1]), THRED);

    float4* wsHead = (float4*)ws;
    float4* wsV0   = wsHead + WS_F4_STRIDE;
    float4* wsV1   = wsV0 + WS_F4_STRIDE;
    float2* wsKt   = (float2*)(wsV1 + WS_F4_STRIDE);

    const int idx = b * HID + h;
    wsHead[idx] = hd;
    wsV0[idx]   = norm4(rr[0]);
    wsV1[idx]   = norm4(rr[1]);
    wsKt[idx]   = make_float2(kt0, kt1);
}

// ---- Kernel B: cooperative gather + score, 4 negs batched per iteration.
//      Row loads are nontemporal (no reuse beyond the 1.79x dup factor;
//      keep them out of L2 allocation — A/B vs R7's plain loads). ----
__global__ __launch_bounds__(BLOCK, 5) void house_score_kernel(
    const float* __restrict__ ent,
    const int* __restrict__ tail_idx,
    const float* __restrict__ ws,
    float* __restrict__ out)
{
    const int blk = blockIdx.x;
    const int b   = blk >> 2;          // SEGS = 4
    const int seg = blk & (SEGS - 1);
    const int tid = threadIdx.x;
    const int w = tid >> 6;   // wave in block
    const int l = tid & 63;   // lane

    const float4* wsHead = (const float4*)ws;
    const float4* wsV0   = wsHead + WS_F4_STRIDE;
    const float4* wsV1   = wsV0 + WS_F4_STRIDE;
    const float2* wsKt   = (const float2*)(wsV1 + WS_F4_STRIDE);

    // lane l owns hids {l, 64+l (l<36)}
    const int i1 = b * HID + l;
    const float4 hd1 = wsHead[i1];
    const float4 v01 = wsV0[i1];
    const float4 v11 = wsV1[i1];
    const float2 k1  = wsKt[i1];
    const int   l2   = (l < 36) ? (64 + l) : 99;
    const int   i2   = b * HID + l2;
    const float4 hd2 = wsHead[i2];
    const float4 v02 = wsV0[i2];
    const float4 v12 = wsV1[i2];
    const float2 k2  = wsKt[i2];
    const bool has2  = (l < 36);

    const int negbase = seg * NEG_PER_BLOCK + w * NEG_PER_WAVE;

    // this wave's 16 tail indices live in lanes 0..15
    int my_e = 0;
    if (l < NEG_PER_WAVE) my_e = tail_idx[(size_t)b * NEG + negbase + l];

    const float4* entf4 = (const float4*)ent;

    for (int ii = 0; ii < NEG_PER_WAVE; ii += 4) {
        const int e0 = __shfl(my_e, ii + 0);
        const int e1 = __shfl(my_e, ii + 1);
        const int e2 = __shfl(my_e, ii + 2);
        const int e3 = __shfl(my_e, ii + 3);
        const float4* r0 = entf4 + (size_t)e0 * HID;
        const float4* r1 = entf4 + (size_t)e1 * HID;
        const float4* r2 = entf4 + (size_t)e2 * HID;
        const float4* r3 = entf4 + (size_t)e3 * HID;

        // issue all 8 row-segment loads before any compute (deep MLP)
        const float4 a0 = ntload4(r0 + l);
        const float4 a1 = ntload4(r1 + l);
        const float4 a2 = ntload4(r2 + l);
        const float4 a3 = ntload4(r3 + l);
        float4 b0, b1, b2, b3;
        if (has2) {
            b0 = ntload4(r0 + 64 + l);
            b1 = ntload4(r1 + 64 + l);
            b2 = ntload4(r2 + 64 + l);
            b3 = ntload4(r3 + 64 + l);
        }

        float s0 = hdist(a0, v01, v11, k1, hd1);
        float s1 = hdist(a1, v01, v11, k1, hd1);
        float s2 = hdist(a2, v01, v11, k1, hd1);
        float s3 = hdist(a3, v01, v11, k1, hd1);
        if (has2) {
            s0 += hdist(b0, v02, v12, k2, hd2);
            s1 += hdist(b1, v02, v12, k2, hd2);
            s2 += hdist(b2, v02, v12, k2, hd2);
            s3 += hdist(b3, v02, v12, k2, hd2);
        }

        // 4 interleaved butterfly reductions (independent DS chains)
        #pragma unroll
        for (int m = 1; m < 64; m <<= 1) {
            s0 += __shfl_xor(s0, m);
            s1 += __shfl_xor(s1, m);
            s2 += __shfl_xor(s2, m);
            s3 += __shfl_xor(s3, m);
        }

        if (l == 0) {
            float4 o = make_float4(GAMMA - s0, GAMMA - s1, GAMMA - s2, GAMMA - s3);
            *(float4*)(out + (size_t)b * NEG + negbase + ii) = o;
        }
    }
}

extern "C" void kernel_launch(void* const* d_in, const int* in_sizes, int n_in,
                              void* d_out, int out_size, void* d_ws, size_t ws_size,
                              hipStream_t stream) {
    const float* ent = (const float*)d_in[0];
    const float* rel = (const float*)d_in[1];
    const float* kdh = (const float*)d_in[2];
    const float* kdt = (const float*)d_in[3];
    const float* ksh = (const float*)d_in[4];
    const float* kst = (const float*)d_in[5];
    const int* head_idx = (const int*)d_in[6];
    const int* rel_idx  = (const int*)d_in[7];
    const int* tail_idx = (const int*)d_in[8];
    float* out = (float*)d_out;
    float* ws  = (float*)d_ws;

    house_prep_kernel<<<B_SZ, 128, 0, stream>>>(
        ent, rel, kdh, kdt, ksh, kst, head_idx, rel_idx, ws);
    house_score_kernel<<<B_SZ * SEGS, BLOCK, 0, stream>>>(
        ent, tail_idx, ws, out);
}